// Round 5
// baseline (75.211 us; speedup 1.0000x reference)
//
#include <hip/hip_runtime.h>
#include <hip/hip_bf16.h>

#define N_TOT 8192
#define DIM 256
#define HALF_B 4096
#define NCHUNK 32                            // 256-row chunks
#define NPAIR (NCHUNK * (NCHUNK + 1) / 2)    // 528 upper-tri pairs
#define NBLK (NPAIR * 2)                     // 1056 half-blocks
#define TILE_COLS 64
#define NTILES 2                             // 2 x 64 = 128 cols per block
#define ROWS_PER_WAVE 64
#define ROWS_PER_BLOCK 256                   // 4 waves
#define NSLOT 96                             // 64 rowsum(half-chunk) + 32 colsum(chunk)
#define LSE_BLOCKS (N_TOT / 4)               // 2048
#define KEXP 2.8853900817779268f             // (1/T=2) * log2(e)
#define TILE_USHORTS (TILE_COLS * DIM)       // 16384 ushorts = 32KB

typedef __attribute__((ext_vector_type(8))) short bfrag;   // 8 bf16 = 4 VGPRs
typedef __attribute__((ext_vector_type(4))) float facc;    // 4 f32 accum

typedef __attribute__((address_space(1))) const unsigned int guint;
typedef __attribute__((address_space(3))) unsigned int luint;

static __device__ __forceinline__ void gload16(const void* g, void* l) {
    __builtin_amdgcn_global_load_lds((guint*)g, (luint*)l, 16, 0, 0);
}
static __device__ __forceinline__ unsigned short f2bf(float x) {
    __hip_bfloat16 h = __float2bfloat16(x);
    return __builtin_bit_cast(unsigned short, h);
}
static __device__ __forceinline__ float b2f(unsigned short u) {
    unsigned int v = ((unsigned int)u) << 16;
    return __builtin_bit_cast(float, v);
}
static __device__ __forceinline__ float fast_exp2(float x) {
#if __has_builtin(__builtin_amdgcn_exp2f)
    return __builtin_amdgcn_exp2f(x);
#else
    return exp2f(x);
#endif
}

// Kernel 1: row-normalize concat(z_i, z_j) -> zn bf16 [N_TOT][DIM]
__global__ __launch_bounds__(256) void norm_kernel(const float* __restrict__ zi,
                                                   const float* __restrict__ zj,
                                                   unsigned short* __restrict__ zn) {
    int row  = blockIdx.x * 4 + (threadIdx.x >> 6);
    int lane = threadIdx.x & 63;
    const float* src = (row < HALF_B) ? (zi + (size_t)row * DIM)
                                      : (zj + (size_t)(row - HALF_B) * DIM);
    float4 v = reinterpret_cast<const float4*>(src)[lane];
    float ss = v.x * v.x + v.y * v.y + v.z * v.z + v.w * v.w;
    #pragma unroll
    for (int off = 32; off; off >>= 1) ss += __shfl_xor(ss, off);
    float inv = 1.0f / fmaxf(sqrtf(ss), 1e-8f);
    ushort4 o;
    o.x = f2bf(v.x * inv);
    o.y = f2bf(v.y * inv);
    o.z = f2bf(v.z * inv);
    o.w = f2bf(v.w * inv);
    reinterpret_cast<ushort4*>(zn + (size_t)row * DIM)[lane] = o;
}

// Kernel 2: symmetric fused zn@zn^T + exp sums.
// Block = pair-half (i,j,h): rows chunk i (256), cols = chunk j half h (128).
// Upper triangle only (i<=j): rowsum -> partial[2j+h][rows of i];
// colsum (sum over the 256 rows, 4-wave LDS reduce) -> partial[64+i][cols].
// Diagonal pair masks self and skips colsum. Every (slot,row) written once.
__global__ __launch_bounds__(256, 2) void sim_kernel(const unsigned short* __restrict__ zn,
                                                     float* __restrict__ partial) {
    __shared__ __align__(16) unsigned short smem[2 * TILE_USHORTS];   // 64KB dbuf
    __shared__ float colred[4][128];                                  // 2KB
    const int lane = threadIdx.x & 63;
    const int wv   = threadIdx.x >> 6;
    const int lrow = lane & 15;         // A-row / B-col within 16
    const int kq   = lane >> 4;         // k-group 0..3
    const int swzE = (lrow & 7) << 3;   // XOR swizzle (elements)

    // decode block -> (i, j, h): pair upper-tri enumeration
    const int pairId = blockIdx.x >> 1;
    const int h      = blockIdx.x & 1;
    int i = 0, rem = pairId;
    while (rem >= NCHUNK - i) { rem -= NCHUNK - i; ++i; }
    const int j = i + rem;
    const int rowBase  = i * 256 + wv * 64;
    const int colStart = j * 256 + h * 128;

    // staging address precompute (pre-swizzled source, lane-linear LDS dest)
    int srcOff[8];
    #pragma unroll
    for (int q = 0; q < 8; ++q) {
        int c  = (wv * 8 + q) * 64 + lane;   // 16B-chunk id 0..2047
        int r  = c >> 5;                     // tile row 0..63
        int cc = c & 31;                     // 16B-chunk within row
        srcOff[q] = r * DIM + ((cc * 8) ^ ((r & 7) << 3));
    }
    const unsigned short* znT = zn + (size_t)colStart * DIM;

#define STAGE(buf, ct) do {                                                   \
        const unsigned short* gsb = znT + (size_t)(ct) * (TILE_COLS * DIM);   \
        _Pragma("unroll")                                                     \
        for (int q = 0; q < 8; ++q)                                           \
            gload16(gsb + srcOff[q],                                          \
                    smem + (buf) * TILE_USHORTS + (wv * 8 + q) * 512);        \
    } while (0)

    STAGE(0, 0);

    // A fragments: 4 row-tiles x 8 ksteps, resident all loop long
    bfrag a[4][8];
    #pragma unroll
    for (int t = 0; t < 4; ++t)
        #pragma unroll
        for (int ks = 0; ks < 8; ++ks)
            a[t][ks] = *reinterpret_cast<const bfrag*>(
                zn + (size_t)(rowBase + t * 16 + lrow) * DIM + ks * 32 + kq * 8);
    #pragma unroll
    for (int t = 0; t < 4; ++t)
        #pragma unroll
        for (int ks = 0; ks < 8; ++ks)
            asm volatile("" : "+v"(a[t][ks]));

    float rowsum[4][4];
    #pragma unroll
    for (int t = 0; t < 4; ++t)
        #pragma unroll
        for (int jj = 0; jj < 4; ++jj) rowsum[t][jj] = 0.0f;
    float colAcc[NTILES * 4];   // per (tile, cs) col-subtile, static indexed

    __syncthreads();            // tile 0 staged (A loads also drained)

    #pragma unroll              // full unroll: colAcc indexes stay constant
    for (int tile = 0; tile < NTILES; ++tile) {
        const int cur = tile & 1;
        if (tile + 1 < NTILES) STAGE(cur ^ 1, tile + 1);   // hides under MFMA

        #pragma unroll
        for (int cs = 0; cs < 4; ++cs) {                   // 16-col subtiles
            const unsigned short* base =
                smem + cur * TILE_USHORTS + (cs * 16 + lrow) * DIM;
            bfrag bb[8];
            #pragma unroll
            for (int ks = 0; ks < 8; ++ks)
                bb[ks] = *reinterpret_cast<const bfrag*>(
                    base + ((ks * 32 + kq * 8) ^ swzE));
            facc acc[4];
            #pragma unroll
            for (int t = 0; t < 4; ++t) acc[t] = (facc){0.f, 0.f, 0.f, 0.f};
            #pragma unroll
            for (int ks = 0; ks < 8; ++ks)
                #pragma unroll
                for (int t = 0; t < 4; ++t)
                    acc[t] = __builtin_amdgcn_mfma_f32_16x16x32_bf16(
                        a[t][ks], bb[ks], acc[t], 0, 0, 0);

            const int colBase = colStart + tile * TILE_COLS + cs * 16;
            float csum = 0.0f;
            #pragma unroll
            for (int t = 0; t < 4; ++t) {
                const int tRowBase = rowBase + t * 16;
                if (colBase == tRowBase) {                 // self-diagonal tile
                    #pragma unroll
                    for (int jj = 0; jj < 4; ++jj) {
                        float e = fast_exp2(acc[t][jj] * KEXP);
                        if (lrow == kq * 4 + jj) e = 0.0f; // exclude self
                        rowsum[t][jj] += e;
                        csum += e;
                    }
                } else {
                    #pragma unroll
                    for (int jj = 0; jj < 4; ++jj) {
                        float e = fast_exp2(acc[t][jj] * KEXP);
                        rowsum[t][jj] += e;
                        csum += e;
                    }
                }
            }
            colAcc[tile * 4 + cs] = csum;
        }
        __syncthreads();   // next tile staged; reads of buf[cur] done
    }
#undef STAGE

    // rowsum: reduce across the 16 lrow lanes -> partial[2j+h][row]
    const int slotR = j * 2 + h;
    #pragma unroll
    for (int t = 0; t < 4; ++t)
        #pragma unroll
        for (int jj = 0; jj < 4; ++jj) {
            float v = rowsum[t][jj];
            v += __shfl_xor(v, 1);
            v += __shfl_xor(v, 2);
            v += __shfl_xor(v, 4);
            v += __shfl_xor(v, 8);
            if (lrow == 0)
                partial[(size_t)slotR * N_TOT + rowBase + t * 16 + kq * 4 + jj] = v;
        }

    // colsum: reduce across kq groups in-wave, then across the 4 waves in LDS
    if (i != j) {
        #pragma unroll
        for (int q = 0; q < NTILES * 4; ++q) {
            float v = colAcc[q];
            v += __shfl_xor(v, 16);
            v += __shfl_xor(v, 32);
            if (kq == 0) colred[wv][q * 16 + lrow] = v;
        }
        __syncthreads();
        if (threadIdx.x < 128) {
            int c = threadIdx.x;
            float s = colred[0][c] + colred[1][c] + colred[2][c] + colred[3][c];
            partial[(size_t)(64 + i) * N_TOT + colStart + c] = s;
        }
    }
}

// Kernel 3: one wave per row: S = sum of valid slots; lse = log(S);
// pos = 2*dot(zn[r], zn[r^B]) computed directly in f32.
__global__ __launch_bounds__(256) void lse_kernel(const unsigned short* __restrict__ zn,
                                                  const float* __restrict__ partial,
                                                  float* __restrict__ blockSums) {
    const int lane = threadIdx.x & 63;
    const int wv   = threadIdx.x >> 6;
    const int r    = blockIdx.x * 4 + wv;
    const int rb   = r >> 8;
    const int rp   = r ^ HALF_B;
    ushort4 va = reinterpret_cast<const ushort4*>(zn + (size_t)r  * DIM)[lane];
    ushort4 vb = reinterpret_cast<const ushort4*>(zn + (size_t)rp * DIM)[lane];
    float d = b2f(va.x) * b2f(vb.x) + b2f(va.y) * b2f(vb.y) +
              b2f(va.z) * b2f(vb.z) + b2f(va.w) * b2f(vb.w);
    float S = 0.0f;
    if (lane >= 2 * rb) S += partial[(size_t)lane * N_TOT + r];          // rowsum slots
    if (lane < rb)      S += partial[(size_t)(64 + lane) * N_TOT + r];   // colsum slots
    float red2 = S + d;   // placeholder to keep both reduces together
    (void)red2;
    #pragma unroll
    for (int off = 32; off; off >>= 1) {
        d += __shfl_xor(d, off);
        S += __shfl_xor(S, off);
    }
    __shared__ float red[4];
    if (lane == 0) red[wv] = logf(S) - d * 2.0f;
    __syncthreads();
    if (threadIdx.x == 0)
        blockSums[blockIdx.x] = red[0] + red[1] + red[2] + red[3];
}

// Kernel 4: reduce 2048 block sums -> loss
__global__ __launch_bounds__(256) void final_kernel(const float* __restrict__ bs,
                                                    float* __restrict__ out) {
    int t = threadIdx.x;
    float v = 0.0f;
    #pragma unroll
    for (int q = 0; q < LSE_BLOCKS / 256; ++q) v += bs[t + q * 256];
    #pragma unroll
    for (int off = 32; off; off >>= 1) v += __shfl_xor(v, off);
    __shared__ float red[4];
    if ((t & 63) == 0) red[t >> 6] = v;
    __syncthreads();
    if (t == 0) out[0] = (red[0] + red[1] + red[2] + red[3]) / (float)N_TOT;
}

extern "C" void kernel_launch(void* const* d_in, const int* in_sizes, int n_in,
                              void* d_out, int out_size, void* d_ws, size_t ws_size,
                              hipStream_t stream) {
    const float* zi = (const float*)d_in[0];
    const float* zj = (const float*)d_in[1];
    char* ws = (char*)d_ws;

    unsigned short* zn = (unsigned short*)ws;                        // 4 MB
    float* partial    = (float*)(ws + (size_t)N_TOT * DIM * 2);      // 96 slots = 3 MB
    float* blockSums  = partial + (size_t)NSLOT * N_TOT;             // 8 KB
    float* out        = (float*)d_out;

    norm_kernel<<<N_TOT / 4, 256, 0, stream>>>(zi, zj, zn);
    sim_kernel<<<NBLK, 256, 0, stream>>>(zn, partial);
    lse_kernel<<<LSE_BLOCKS, 256, 0, stream>>>(zn, partial, blockSums);
    final_kernel<<<1, 256, 0, stream>>>(blockSums, out);
}

// Round 6
// 67.690 us; speedup vs baseline: 1.1111x; 1.1111x over previous
//
#include <hip/hip_runtime.h>
#include <hip/hip_bf16.h>

#define N_TOT 8192
#define DIM 256
#define HALF_B 4096
#define NCHUNK 32                            // 256-row chunks
#define NPAIR (NCHUNK * (NCHUNK + 1) / 2)    // 528 upper-tri pairs
#define NBLK (NPAIR * 2)                     // 1056 half-blocks
#define TILE_COLS 64
#define NTILES 2                             // 2 x 64 = 128 cols per block
#define ROWS_PER_WAVE 64
#define ROWS_PER_BLOCK 256                   // 4 waves
#define NSLOT 96                             // 64 rowsum(half-chunk) + 32 colsum(chunk)
#define LSE_BLOCKS (N_TOT / 4)               // 2048
#define KEXP 2.8853900817779268f             // (1/T=2) * log2(e)
#define TILE_USHORTS (TILE_COLS * DIM)       // 16384 ushorts = 32KB

typedef __attribute__((ext_vector_type(8))) short bfrag;   // 8 bf16 = 4 VGPRs
typedef __attribute__((ext_vector_type(4))) float facc;    // 4 f32 accum

typedef __attribute__((address_space(1))) const unsigned int guint;
typedef __attribute__((address_space(3))) unsigned int luint;

static __device__ __forceinline__ void gload16(const void* g, void* l) {
    __builtin_amdgcn_global_load_lds((guint*)g, (luint*)l, 16, 0, 0);
}
static __device__ __forceinline__ unsigned short f2bf(float x) {
    __hip_bfloat16 h = __float2bfloat16(x);
    return __builtin_bit_cast(unsigned short, h);
}
static __device__ __forceinline__ float b2f(unsigned short u) {
    unsigned int v = ((unsigned int)u) << 16;
    return __builtin_bit_cast(float, v);
}
static __device__ __forceinline__ float fast_exp2(float x) {
#if __has_builtin(__builtin_amdgcn_exp2f)
    return __builtin_amdgcn_exp2f(x);
#else
    return exp2f(x);
#endif
}

// Kernel 1: row-normalize concat(z_i, z_j) -> zn bf16 [N_TOT][DIM]
__global__ __launch_bounds__(256) void norm_kernel(const float* __restrict__ zi,
                                                   const float* __restrict__ zj,
                                                   unsigned short* __restrict__ zn) {
    int row  = blockIdx.x * 4 + (threadIdx.x >> 6);
    int lane = threadIdx.x & 63;
    const float* src = (row < HALF_B) ? (zi + (size_t)row * DIM)
                                      : (zj + (size_t)(row - HALF_B) * DIM);
    float4 v = reinterpret_cast<const float4*>(src)[lane];
    float ss = v.x * v.x + v.y * v.y + v.z * v.z + v.w * v.w;
    #pragma unroll
    for (int off = 32; off; off >>= 1) ss += __shfl_xor(ss, off);
    float inv = 1.0f / fmaxf(sqrtf(ss), 1e-8f);
    ushort4 o;
    o.x = f2bf(v.x * inv);
    o.y = f2bf(v.y * inv);
    o.z = f2bf(v.z * inv);
    o.w = f2bf(v.w * inv);
    reinterpret_cast<ushort4*>(zn + (size_t)row * DIM)[lane] = o;
}

// Kernel 2: symmetric fused zn@zn^T + exp sums.
// Block = pair-half (i,j,h): rows = chunk i (256), cols = chunk j half h (128).
// rowsum -> partial[2j+h][rows of chunk i];
// colsum (i<j only; accumulated in LDS colred, 4-wave reduce at end)
//   -> partial[64+i][cols of this half].
// Register budget: a[4][8]=128 pinned + bb/acc/rowsum transient; NO register
// col accumulator and NO full unroll (both caused round-5 scratch spills).
__global__ __launch_bounds__(256, 2) void sim_kernel(const unsigned short* __restrict__ zn,
                                                     float* __restrict__ partial) {
    __shared__ __align__(16) unsigned short smem[2 * TILE_USHORTS];   // 64KB dbuf
    __shared__ float colred[4][128];                                  // 2KB
    const int lane = threadIdx.x & 63;
    const int wv   = threadIdx.x >> 6;
    const int lrow = lane & 15;         // A-row / B-col within 16
    const int kq   = lane >> 4;         // k-group 0..3
    const int swzE = (lrow & 7) << 3;   // XOR swizzle (elements)

    // decode block -> (i, j, h): pair upper-tri enumeration (block-uniform SALU)
    const int pairId = blockIdx.x >> 1;
    const int h      = blockIdx.x & 1;
    int i = 0, rem = pairId;
    while (rem >= NCHUNK - i) { rem -= NCHUNK - i; ++i; }
    const int j = i + rem;
    const int rowBase  = i * 256 + wv * 64;
    const int colStart = j * 256 + h * 128;

    // staging address precompute (pre-swizzled source, lane-linear LDS dest)
    int srcOff[8];
    #pragma unroll
    for (int q = 0; q < 8; ++q) {
        int c  = (wv * 8 + q) * 64 + lane;   // 16B-chunk id 0..2047
        int r  = c >> 5;                     // tile row 0..63
        int cc = c & 31;                     // 16B-chunk within row
        srcOff[q] = r * DIM + ((cc * 8) ^ ((r & 7) << 3));
    }
    const unsigned short* znT = zn + (size_t)colStart * DIM;

#define STAGE(buf, ct) do {                                                   \
        const unsigned short* gsb = znT + (size_t)(ct) * (TILE_COLS * DIM);   \
        _Pragma("unroll")                                                     \
        for (int q = 0; q < 8; ++q)                                           \
            gload16(gsb + srcOff[q],                                          \
                    smem + (buf) * TILE_USHORTS + (wv * 8 + q) * 512);        \
    } while (0)

    STAGE(0, 0);

    // A fragments: 4 row-tiles x 8 ksteps, resident all loop long
    bfrag a[4][8];
    #pragma unroll
    for (int t = 0; t < 4; ++t)
        #pragma unroll
        for (int ks = 0; ks < 8; ++ks)
            a[t][ks] = *reinterpret_cast<const bfrag*>(
                zn + (size_t)(rowBase + t * 16 + lrow) * DIM + ks * 32 + kq * 8);
    #pragma unroll
    for (int t = 0; t < 4; ++t)
        #pragma unroll
        for (int ks = 0; ks < 8; ++ks)
            asm volatile("" : "+v"(a[t][ks]));

    float rowsum[4][4];
    #pragma unroll
    for (int t = 0; t < 4; ++t)
        #pragma unroll
        for (int jj = 0; jj < 4; ++jj) rowsum[t][jj] = 0.0f;

    // zero this wave's colred row (each wave owns colred[wv][0..127])
    colred[wv][lane]      = 0.0f;
    colred[wv][lane + 64] = 0.0f;

    __syncthreads();            // tile 0 staged; colred zeroed

    #pragma unroll 1
    for (int tile = 0; tile < NTILES; ++tile) {
        const int cur = tile & 1;
        if (tile + 1 < NTILES) STAGE(cur ^ 1, tile + 1);   // hides under MFMA

        #pragma unroll
        for (int cs = 0; cs < 4; ++cs) {                   // 16-col subtiles
            const unsigned short* base =
                smem + cur * TILE_USHORTS + (cs * 16 + lrow) * DIM;
            bfrag bb[8];
            #pragma unroll
            for (int ks = 0; ks < 8; ++ks)
                bb[ks] = *reinterpret_cast<const bfrag*>(
                    base + ((ks * 32 + kq * 8) ^ swzE));
            facc acc[4];
            #pragma unroll
            for (int t = 0; t < 4; ++t) acc[t] = (facc){0.f, 0.f, 0.f, 0.f};
            #pragma unroll
            for (int ks = 0; ks < 8; ++ks)
                #pragma unroll
                for (int t = 0; t < 4; ++t)
                    acc[t] = __builtin_amdgcn_mfma_f32_16x16x32_bf16(
                        a[t][ks], bb[ks], acc[t], 0, 0, 0);

            const int colBase = colStart + tile * TILE_COLS + cs * 16;
            float csum = 0.0f;
            #pragma unroll
            for (int t = 0; t < 4; ++t) {
                const int tRowBase = rowBase + t * 16;
                if (colBase == tRowBase) {                 // self-diagonal tile
                    #pragma unroll
                    for (int jj = 0; jj < 4; ++jj) {
                        float e = fast_exp2(acc[t][jj] * KEXP);
                        if (lrow == kq * 4 + jj) e = 0.0f; // exclude self
                        rowsum[t][jj] += e;
                        csum += e;
                    }
                } else {
                    #pragma unroll
                    for (int jj = 0; jj < 4; ++jj) {
                        float e = fast_exp2(acc[t][jj] * KEXP);
                        rowsum[t][jj] += e;
                        csum += e;
                    }
                }
            }
            // column-sum: reduce over kq groups, accumulate into LDS (no reg array)
            csum += __shfl_xor(csum, 16);
            csum += __shfl_xor(csum, 32);
            if (kq == 0)
                colred[wv][tile * TILE_COLS + cs * 16 + lrow] += csum;
        }
        __syncthreads();   // next tile staged; reads of buf[cur] done
    }
#undef STAGE

    // rowsum: reduce across the 16 lrow lanes -> partial[2j+h][row]
    const int slotR = j * 2 + h;
    #pragma unroll
    for (int t = 0; t < 4; ++t)
        #pragma unroll
        for (int jj = 0; jj < 4; ++jj) {
            float v = rowsum[t][jj];
            v += __shfl_xor(v, 1);
            v += __shfl_xor(v, 2);
            v += __shfl_xor(v, 4);
            v += __shfl_xor(v, 8);
            if (lrow == 0)
                partial[(size_t)slotR * N_TOT + rowBase + t * 16 + kq * 4 + jj] = v;
        }

    // colsum: cross-wave reduce of colred (last __syncthreads made it visible)
    if (i != j && threadIdx.x < 128) {
        int c = threadIdx.x;
        float s = colred[0][c] + colred[1][c] + colred[2][c] + colred[3][c];
        partial[(size_t)(64 + i) * N_TOT + colStart + c] = s;
    }
}

// Kernel 3: one wave per row: S = sum of valid slots; lse = log(S);
// pos = 2*dot(zn[r], zn[r^B]) computed directly in f32.
__global__ __launch_bounds__(256) void lse_kernel(const unsigned short* __restrict__ zn,
                                                  const float* __restrict__ partial,
                                                  float* __restrict__ blockSums) {
    const int lane = threadIdx.x & 63;
    const int wv   = threadIdx.x >> 6;
    const int r    = blockIdx.x * 4 + wv;
    const int rb   = r >> 8;
    const int rp   = r ^ HALF_B;
    ushort4 va = reinterpret_cast<const ushort4*>(zn + (size_t)r  * DIM)[lane];
    ushort4 vb = reinterpret_cast<const ushort4*>(zn + (size_t)rp * DIM)[lane];
    float d = b2f(va.x) * b2f(vb.x) + b2f(va.y) * b2f(vb.y) +
              b2f(va.z) * b2f(vb.z) + b2f(va.w) * b2f(vb.w);
    float S = 0.0f;
    if (lane >= 2 * rb) S += partial[(size_t)lane * N_TOT + r];          // rowsum slots
    if (lane < rb)      S += partial[(size_t)(64 + lane) * N_TOT + r];   // colsum slots
    #pragma unroll
    for (int off = 32; off; off >>= 1) {
        d += __shfl_xor(d, off);
        S += __shfl_xor(S, off);
    }
    __shared__ float red[4];
    if (lane == 0) red[wv] = logf(S) - d * 2.0f;
    __syncthreads();
    if (threadIdx.x == 0)
        blockSums[blockIdx.x] = red[0] + red[1] + red[2] + red[3];
}

// Kernel 4: reduce 2048 block sums -> loss
__global__ __launch_bounds__(256) void final_kernel(const float* __restrict__ bs,
                                                    float* __restrict__ out) {
    int t = threadIdx.x;
    float v = 0.0f;
    #pragma unroll
    for (int q = 0; q < LSE_BLOCKS / 256; ++q) v += bs[t + q * 256];
    #pragma unroll
    for (int off = 32; off; off >>= 1) v += __shfl_xor(v, off);
    __shared__ float red[4];
    if ((t & 63) == 0) red[t >> 6] = v;
    __syncthreads();
    if (t == 0) out[0] = (red[0] + red[1] + red[2] + red[3]) / (float)N_TOT;
}

extern "C" void kernel_launch(void* const* d_in, const int* in_sizes, int n_in,
                              void* d_out, int out_size, void* d_ws, size_t ws_size,
                              hipStream_t stream) {
    const float* zi = (const float*)d_in[0];
    const float* zj = (const float*)d_in[1];
    char* ws = (char*)d_ws;

    unsigned short* zn = (unsigned short*)ws;                        // 4 MB
    float* partial    = (float*)(ws + (size_t)N_TOT * DIM * 2);      // 96 slots = 3 MB
    float* blockSums  = partial + (size_t)NSLOT * N_TOT;             // 8 KB
    float* out        = (float*)d_out;

    norm_kernel<<<N_TOT / 4, 256, 0, stream>>>(zi, zj, zn);
    sim_kernel<<<NBLK, 256, 0, stream>>>(zn, partial);
    lse_kernel<<<LSE_BLOCKS, 256, 0, stream>>>(zn, partial, blockSums);
    final_kernel<<<1, 256, 0, stream>>>(blockSums, out);
}

// Round 7
// 58.484 us; speedup vs baseline: 1.2860x; 1.1574x over previous
//
#include <hip/hip_runtime.h>
#include <hip/hip_bf16.h>
#include <hip/hip_fp8.h>

#define N_TOT 8192
#define DIM 256                              // k elements = bytes (fp8)
#define HALF_B 4096
#define NCHUNK 32                            // 256-row chunks
#define NPAIR (NCHUNK * (NCHUNK + 1) / 2)    // 528 upper-tri pairs
#define NBLK (NPAIR * 2)                     // 1056 half-blocks
#define TILE_COLS 64
#define NTILES 2                             // 2 x 64 = 128 cols per block
#define NSLOT 96                             // 64 rowsum + 32 colsum slots
#define LSE_BLOCKS (N_TOT / 4)               // 2048
#define KEXP 2.8853900817779268f             // (1/T=2) * log2(e)
#define TILE_BYTES (TILE_COLS * DIM)         // 16384 B = 16KB per staged tile

typedef __attribute__((ext_vector_type(4))) float facc;      // 4 f32 accum
typedef __attribute__((ext_vector_type(2))) long long lpair; // 16B = 2 fp8 ksteps

typedef __attribute__((address_space(1))) const unsigned int guint;
typedef __attribute__((address_space(3))) unsigned int luint;

static __device__ __forceinline__ void gload16(const void* g, void* l) {
    __builtin_amdgcn_global_load_lds((guint*)g, (luint*)l, 16, 0, 0);
}
static __device__ __forceinline__ unsigned char f2fp8(float x) {
    __hip_fp8_e4m3 h(x);
    return (unsigned char)h.__x;
}
static __device__ __forceinline__ float fp82f(unsigned char b) {
    __hip_fp8_e4m3 h; h.__x = (__hip_fp8_storage_t)b;
    return (float)h;
}
static __device__ __forceinline__ float fast_exp2(float x) {
#if __has_builtin(__builtin_amdgcn_exp2f)
    return __builtin_amdgcn_exp2f(x);
#else
    return exp2f(x);
#endif
}
static __device__ __forceinline__ facc mfma8(long long a, long long b, facc c) {
    return __builtin_amdgcn_mfma_f32_16x16x32_fp8_fp8(a, b, c, 0, 0, 0);
}

// Kernel 1: row-normalize concat(z_i, z_j) -> fp8 zn, TWO layouts:
//  znN: natural k-order (A-frag loads + lse pos-dot)
//  znP: per-row kq-major permute (B staging: 16B chunk = k-pair, gload16-able)
__global__ __launch_bounds__(256) void norm_kernel(const float* __restrict__ zi,
                                                   const float* __restrict__ zj,
                                                   unsigned char* __restrict__ znN,
                                                   unsigned char* __restrict__ znP) {
    int row  = blockIdx.x * 4 + (threadIdx.x >> 6);
    int lane = threadIdx.x & 63;
    const float* src = (row < HALF_B) ? (zi + (size_t)row * DIM)
                                      : (zj + (size_t)(row - HALF_B) * DIM);
    float4 v = reinterpret_cast<const float4*>(src)[lane];
    float ss = v.x * v.x + v.y * v.y + v.z * v.z + v.w * v.w;
    #pragma unroll
    for (int off = 32; off; off >>= 1) ss += __shfl_xor(ss, off);
    float inv = 1.0f / fmaxf(sqrtf(ss), 1e-8f);
    uchar4 o;
    o.x = f2fp8(v.x * inv);
    o.y = f2fp8(v.y * inv);
    o.z = f2fp8(v.z * inv);
    o.w = f2fp8(v.w * inv);
    int b = lane * 4;                 // natural byte offset (granule g, half i)
    int g = b >> 3;                   // granule 0..31: ks = g>>2, kq = g&3
    int pb = ((((g & 3) << 3) | (g >> 2)) << 3) | (b & 7);   // kq-major position
    *reinterpret_cast<uchar4*>(znN + (size_t)row * DIM + b)  = o;
    *reinterpret_cast<uchar4*>(znP + (size_t)row * DIM + pb) = o;
}

// Kernel 2: symmetric fused zn@zn^T (fp8 MFMA) + exp sums.
// Block = pair-half (i,j,h): rows = chunk i (256), cols = chunk j half h (128).
// A: 64 rows/wave resident as long long a[4][8] (64 VGPRs, fp8).
// B: 64-col x 256-B tiles staged from znP via gload16, chunk-XOR swizzle
//    (LDS chunk Q of row r holds source k-pair Q^(r&15); read phase-conflict-free).
// rowsum -> partial[2j+h][rows of i]; colsum (i<j) -> partial[64+i][cols].
__global__ __launch_bounds__(256, 3) void sim_kernel(const unsigned char* __restrict__ znN,
                                                     const unsigned char* __restrict__ znP,
                                                     float* __restrict__ partial) {
    __shared__ __align__(16) unsigned char smem[2 * TILE_BYTES];   // 32KB dbuf
    __shared__ float colred[4][128];                               // 2KB
    const int lane = threadIdx.x & 63;
    const int wv   = threadIdx.x >> 6;
    const int lrow = lane & 15;         // A-row / B-col within 16
    const int kq   = lane >> 4;         // k-group 0..3

    // decode block -> (i, j, h): upper-tri pair enumeration (block-uniform)
    const int pairId = blockIdx.x >> 1;
    const int h      = blockIdx.x & 1;
    int i = 0, rem = pairId;
    while (rem >= NCHUNK - i) { rem -= NCHUNK - i; ++i; }
    const int j = i + rem;
    const int rowBase  = i * 256 + wv * 64;
    const int colStart = j * 256 + h * 128;

    // staging: tile = 64 rows x 16 chunks(16B) = 1024 chunks; 4 per thread
    int srcOff[4];
    #pragma unroll
    for (int q = 0; q < 4; ++q) {
        int c  = (wv * 4 + q) * 64 + lane;   // chunk id 0..1023
        int r  = c >> 4;                     // tile row 0..63
        int cc = c & 15;                     // chunk-in-row (k-pair slot)
        srcOff[q] = r * DIM + ((cc ^ (r & 15)) << 4);   // pre-swizzled source
    }
    const unsigned char* znPC = znP + (size_t)colStart * DIM;

#define STAGE(buf, ct) do {                                                   \
        const unsigned char* gsb = znPC + (size_t)(ct) * TILE_BYTES;          \
        _Pragma("unroll")                                                     \
        for (int q = 0; q < 4; ++q)                                           \
            gload16(gsb + srcOff[q],                                          \
                    smem + (buf) * TILE_BYTES + (wv * 4 + q) * 1024);         \
    } while (0)

    STAGE(0, 0);

    // A fragments: 4 row-tiles x 8 ksteps, 8B each (natural layout)
    long long a[4][8];
    #pragma unroll
    for (int t = 0; t < 4; ++t)
        #pragma unroll
        for (int ks = 0; ks < 8; ++ks)
            a[t][ks] = *reinterpret_cast<const long long*>(
                znN + (size_t)(rowBase + t * 16 + lrow) * DIM + ks * 32 + kq * 8);
    #pragma unroll
    for (int t = 0; t < 4; ++t)
        #pragma unroll
        for (int ks = 0; ks < 8; ++ks)
            asm volatile("" : "+v"(a[t][ks]));

    float rowsum[4][4];
    #pragma unroll
    for (int t = 0; t < 4; ++t)
        #pragma unroll
        for (int jj = 0; jj < 4; ++jj) rowsum[t][jj] = 0.0f;

    colred[wv][lane]      = 0.0f;
    colred[wv][lane + 64] = 0.0f;

    __syncthreads();            // tile 0 staged; colred zeroed

    #pragma unroll 1
    for (int tile = 0; tile < NTILES; ++tile) {
        const int cur = tile & 1;
        if (tile + 1 < NTILES) STAGE(cur ^ 1, tile + 1);   // hides under MFMA

        #pragma unroll
        for (int cs = 0; cs < 4; ++cs) {                   // 16-col subtiles
            const unsigned char* base =
                smem + cur * TILE_BYTES + (cs * 16 + lrow) * DIM;
            facc acc[4];
            #pragma unroll
            for (int t = 0; t < 4; ++t) acc[t] = (facc){0.f, 0.f, 0.f, 0.f};
            #pragma unroll
            for (int s = 0; s < 4; ++s) {                  // k-pair (2 ksteps)
                lpair bv = *reinterpret_cast<const lpair*>(
                    base + (((kq * 4 + s) ^ lrow) << 4));
                #pragma unroll
                for (int t = 0; t < 4; ++t) {
                    acc[t] = mfma8(a[t][2 * s],     bv[0], acc[t]);
                    acc[t] = mfma8(a[t][2 * s + 1], bv[1], acc[t]);
                }
            }

            const int colBase = colStart + tile * TILE_COLS + cs * 16;
            float csum = 0.0f;
            #pragma unroll
            for (int t = 0; t < 4; ++t) {
                const int tRowBase = rowBase + t * 16;
                if (colBase == tRowBase) {                 // self-diagonal tile
                    #pragma unroll
                    for (int jj = 0; jj < 4; ++jj) {
                        float e = fast_exp2(acc[t][jj] * KEXP);
                        if (lrow == kq * 4 + jj) e = 0.0f; // exclude self
                        rowsum[t][jj] += e;
                        csum += e;
                    }
                } else {
                    #pragma unroll
                    for (int jj = 0; jj < 4; ++jj) {
                        float e = fast_exp2(acc[t][jj] * KEXP);
                        rowsum[t][jj] += e;
                        csum += e;
                    }
                }
            }
            // col-sum: reduce across kq groups, accumulate into LDS
            csum += __shfl_xor(csum, 16);
            csum += __shfl_xor(csum, 32);
            if (kq == 0)
                colred[wv][tile * TILE_COLS + cs * 16 + lrow] += csum;
        }
        __syncthreads();   // next tile staged; reads of buf[cur] done
    }
#undef STAGE

    // rowsum: reduce across the 16 lrow lanes -> partial[2j+h][row]
    const int slotR = j * 2 + h;
    #pragma unroll
    for (int t = 0; t < 4; ++t)
        #pragma unroll
        for (int jj = 0; jj < 4; ++jj) {
            float v = rowsum[t][jj];
            v += __shfl_xor(v, 1);
            v += __shfl_xor(v, 2);
            v += __shfl_xor(v, 4);
            v += __shfl_xor(v, 8);
            if (lrow == 0)
                partial[(size_t)slotR * N_TOT + rowBase + t * 16 + kq * 4 + jj] = v;
        }

    // colsum: cross-wave reduce (visible after final __syncthreads)
    if (i != j && threadIdx.x < 128) {
        int c = threadIdx.x;
        float s = colred[0][c] + colred[1][c] + colred[2][c] + colred[3][c];
        partial[(size_t)(64 + i) * N_TOT + colStart + c] = s;
    }
}

// Kernel 3: one wave per row: S = sum of valid slots; lse = log(S);
// pos = 2*dot(zn[r], zn[r^B]) from fp8 decode in f32.
__global__ __launch_bounds__(256) void lse_kernel(const unsigned char* __restrict__ znN,
                                                  const float* __restrict__ partial,
                                                  float* __restrict__ blockSums) {
    const int lane = threadIdx.x & 63;
    const int wv   = threadIdx.x >> 6;
    const int r    = blockIdx.x * 4 + wv;
    const int rb   = r >> 8;
    const int rp   = r ^ HALF_B;
    uchar4 va = *reinterpret_cast<const uchar4*>(znN + (size_t)r  * DIM + lane * 4);
    uchar4 vb = *reinterpret_cast<const uchar4*>(znN + (size_t)rp * DIM + lane * 4);
    float d = fp82f(va.x) * fp82f(vb.x) + fp82f(va.y) * fp82f(vb.y) +
              fp82f(va.z) * fp82f(vb.z) + fp82f(va.w) * fp82f(vb.w);
    float S = 0.0f;
    if (lane >= 2 * rb) S += partial[(size_t)lane * N_TOT + r];          // rowsum slots
    if (lane < rb)      S += partial[(size_t)(64 + lane) * N_TOT + r];   // colsum slots
    #pragma unroll
    for (int off = 32; off; off >>= 1) {
        d += __shfl_xor(d, off);
        S += __shfl_xor(S, off);
    }
    __shared__ float red[4];
    if (lane == 0) red[wv] = logf(S) - d * 2.0f;
    __syncthreads();
    if (threadIdx.x == 0)
        blockSums[blockIdx.x] = red[0] + red[1] + red[2] + red[3];
}

// Kernel 4: reduce 2048 block sums -> loss
__global__ __launch_bounds__(256) void final_kernel(const float* __restrict__ bs,
                                                    float* __restrict__ out) {
    int t = threadIdx.x;
    float v = 0.0f;
    #pragma unroll
    for (int q = 0; q < LSE_BLOCKS / 256; ++q) v += bs[t + q * 256];
    #pragma unroll
    for (int off = 32; off; off >>= 1) v += __shfl_xor(v, off);
    __shared__ float red[4];
    if ((t & 63) == 0) red[t >> 6] = v;
    __syncthreads();
    if (t == 0) out[0] = (red[0] + red[1] + red[2] + red[3]) / (float)N_TOT;
}

extern "C" void kernel_launch(void* const* d_in, const int* in_sizes, int n_in,
                              void* d_out, int out_size, void* d_ws, size_t ws_size,
                              hipStream_t stream) {
    const float* zi = (const float*)d_in[0];
    const float* zj = (const float*)d_in[1];
    char* ws = (char*)d_ws;

    unsigned char* znN = (unsigned char*)ws;                         // 2 MB
    unsigned char* znP = znN + (size_t)N_TOT * DIM;                  // 2 MB
    float* partial    = (float*)(znP + (size_t)N_TOT * DIM);         // 96 slots = 3 MB
    float* blockSums  = partial + (size_t)NSLOT * N_TOT;             // 8 KB
    float* out        = (float*)d_out;

    norm_kernel<<<N_TOT / 4, 256, 0, stream>>>(zi, zj, znN, znP);
    sim_kernel<<<NBLK, 256, 0, stream>>>(znN, znP, partial);
    lse_kernel<<<LSE_BLOCKS, 256, 0, stream>>>(znN, partial, blockSums);
    final_kernel<<<1, 256, 0, stream>>>(blockSums, out);
}

// Round 8
// 40.686 us; speedup vs baseline: 1.8486x; 1.4374x over previous
//
#include <hip/hip_runtime.h>
#include <hip/hip_bf16.h>
#include <hip/hip_fp8.h>

#define N_TOT 8192
#define DIM 256                              // k elements = bytes (fp8)
#define HALF_B 4096
#define NCHUNK 32                            // 256-row chunks
#define NPAIR (NCHUNK * (NCHUNK + 1) / 2)    // 528 upper-tri pairs
#define NBLK (NPAIR * 4)                     // 2112 quarter-blocks (g,h)
#define TILE_COLS 32
#define NTILES 4                             // 4 x 32 = 128 cols per block
#define NSLOT 128                            // 64 rowsum(2j+h) + 64 colsum(2i+g)
#define LSE_BLOCKS (N_TOT / 4)               // 2048
#define KEXP 2.8853900817779268f             // (1/T=2) * log2(e)
#define TILE_BYTES (TILE_COLS * DIM)         // 8192 B per staged tile

typedef __attribute__((ext_vector_type(4))) float facc;      // 4 f32 accum
typedef __attribute__((ext_vector_type(2))) long long lpair; // 16B = 2 fp8 ksteps

typedef __attribute__((address_space(1))) const unsigned int guint;
typedef __attribute__((address_space(3))) unsigned int luint;

static __device__ __forceinline__ void gload16(const void* g, void* l) {
    __builtin_amdgcn_global_load_lds((guint*)g, (luint*)l, 16, 0, 0);
}
static __device__ __forceinline__ unsigned char f2fp8(float x) {
    __hip_fp8_e4m3 h(x);
    return (unsigned char)h.__x;
}
static __device__ __forceinline__ float fp82f(unsigned char b) {
    __hip_fp8_e4m3 h; h.__x = (__hip_fp8_storage_t)b;
    return (float)h;
}
static __device__ __forceinline__ float fast_exp2(float x) {
#if __has_builtin(__builtin_amdgcn_exp2f)
    return __builtin_amdgcn_exp2f(x);
#else
    return exp2f(x);
#endif
}
static __device__ __forceinline__ facc mfma8(long long a, long long b, facc c) {
    return __builtin_amdgcn_mfma_f32_16x16x32_fp8_fp8(a, b, c, 0, 0, 0);
}

// Kernel 1: row-normalize concat(z_i, z_j) -> fp8 znP, kq-major permuted rows
// (16B chunk = k-pair for one kq group; serves A-loads, B-staging, pos-dot).
__global__ __launch_bounds__(256) void norm_kernel(const float* __restrict__ zi,
                                                   const float* __restrict__ zj,
                                                   unsigned char* __restrict__ znP) {
    int row  = blockIdx.x * 4 + (threadIdx.x >> 6);
    int lane = threadIdx.x & 63;
    const float* src = (row < HALF_B) ? (zi + (size_t)row * DIM)
                                      : (zj + (size_t)(row - HALF_B) * DIM);
    float4 v = reinterpret_cast<const float4*>(src)[lane];
    float ss = v.x * v.x + v.y * v.y + v.z * v.z + v.w * v.w;
    #pragma unroll
    for (int off = 32; off; off >>= 1) ss += __shfl_xor(ss, off);
    float inv = 1.0f / fmaxf(sqrtf(ss), 1e-8f);
    uchar4 o;
    o.x = f2fp8(v.x * inv);
    o.y = f2fp8(v.y * inv);
    o.z = f2fp8(v.z * inv);
    o.w = f2fp8(v.w * inv);
    int b = lane * 4;                 // natural byte offset
    int g = b >> 3;                   // granule: natural g = ks*4+kq
    int pb = ((((g & 3) << 3) | (g >> 2)) << 3) | (b & 7);   // permuted = kq*8+ks
    *reinterpret_cast<uchar4*>(znP + (size_t)row * DIM + pb) = o;
}

// Kernel 2: symmetric fused zn@zn^T (fp8 MFMA) + exp sums.
// Block = quarter (i,j,g,h): rows = chunk i half g (128), cols = chunk j half h (128).
// A: 32 rows/wave resident (lpair a[2][4] pairs -> 32 VGPR, allocator-safe).
// B: 32-col x 256-B tiles (8KB) staged via gload16, chunk-XOR swizzle, dbuf.
// rowsum -> partial[2j+h][rows]; colsum (i<j) -> partial[64+2i+g][cols].
__global__ __launch_bounds__(256, 4) void sim_kernel(const unsigned char* __restrict__ znP,
                                                     float* __restrict__ partial) {
    __shared__ __align__(16) unsigned char smem[2 * TILE_BYTES];   // 16KB dbuf
    __shared__ float colred[4][128];                               // 2KB
    const int lane = threadIdx.x & 63;
    const int wv   = threadIdx.x >> 6;
    const int lrow = lane & 15;         // A-row / B-col within 16
    const int kq   = lane >> 4;         // k-group 0..3

    // decode block -> (i, j, g, h)
    const int pairId = blockIdx.x >> 2;
    const int h      = blockIdx.x & 1;
    const int g      = (blockIdx.x >> 1) & 1;
    int i = 0, rem = pairId;
    while (rem >= NCHUNK - i) { rem -= NCHUNK - i; ++i; }
    const int j = i + rem;
    const int rowBase  = i * 256 + g * 128 + wv * 32;
    const int colStart = j * 256 + h * 128;

    // staging: tile = 32 rows x 16 chunks(16B) = 512 chunks; 2 per thread
    int srcOff[2];
    #pragma unroll
    for (int q = 0; q < 2; ++q) {
        int c  = (wv * 2 + q) * 64 + lane;   // chunk id 0..511
        int r  = c >> 4;                     // tile row 0..31
        int cc = c & 15;                     // chunk-in-row (k-pair slot)
        srcOff[q] = r * DIM + ((cc ^ (r & 15)) << 4);   // pre-swizzled source
    }
    const unsigned char* znPC = znP + (size_t)colStart * DIM;

#define STAGE(buf, ct) do {                                                   \
        const unsigned char* gsb = znPC + (size_t)(ct) * TILE_BYTES;          \
        _Pragma("unroll")                                                     \
        for (int q = 0; q < 2; ++q)                                           \
            gload16(gsb + srcOff[q],                                          \
                    smem + (buf) * TILE_BYTES + (wv * 2 + q) * 1024);         \
    } while (0)

    STAGE(0, 0);

    // A fragments: 2 row-tiles x 4 k-pairs (16B each) = 32 VGPRs, resident.
    // znP row layout: bytes [kq*64 + s*16, +16) = ksteps (2s, 2s+1) of group kq.
    lpair a[2][4];
    #pragma unroll
    for (int t = 0; t < 2; ++t)
        #pragma unroll
        for (int s = 0; s < 4; ++s)
            a[t][s] = *reinterpret_cast<const lpair*>(
                znP + (size_t)(rowBase + t * 16 + lrow) * DIM + kq * 64 + s * 16);
    #pragma unroll
    for (int t = 0; t < 2; ++t)
        #pragma unroll
        for (int s = 0; s < 4; ++s)
            asm volatile("" : "+v"(a[t][s]));

    float rowsum[2][4];
    #pragma unroll
    for (int t = 0; t < 2; ++t)
        #pragma unroll
        for (int jj = 0; jj < 4; ++jj) rowsum[t][jj] = 0.0f;

    colred[wv][lane]      = 0.0f;
    colred[wv][lane + 64] = 0.0f;

    __syncthreads();            // tile 0 staged; colred zeroed

    #pragma unroll 1
    for (int tile = 0; tile < NTILES; ++tile) {
        const int cur = tile & 1;
        if (tile + 1 < NTILES) STAGE(cur ^ 1, tile + 1);   // hides under MFMA

        #pragma unroll
        for (int cs = 0; cs < 2; ++cs) {                   // 16-col subtiles
            const unsigned char* base =
                smem + cur * TILE_BYTES + (cs * 16 + lrow) * DIM;
            facc acc[2];
            acc[0] = (facc){0.f, 0.f, 0.f, 0.f};
            acc[1] = (facc){0.f, 0.f, 0.f, 0.f};
            #pragma unroll
            for (int s = 0; s < 4; ++s) {                  // k-pair (2 ksteps)
                lpair bv = *reinterpret_cast<const lpair*>(
                    base + (((kq * 4 + s) ^ lrow) << 4));
                #pragma unroll
                for (int t = 0; t < 2; ++t) {
                    acc[t] = mfma8(a[t][s][0], bv[0], acc[t]);
                    acc[t] = mfma8(a[t][s][1], bv[1], acc[t]);
                }
            }

            const int colBase = colStart + tile * TILE_COLS + cs * 16;
            float csum = 0.0f;
            #pragma unroll
            for (int t = 0; t < 2; ++t) {
                const int tRowBase = rowBase + t * 16;
                if (colBase == tRowBase) {                 // self-diagonal tile
                    #pragma unroll
                    for (int jj = 0; jj < 4; ++jj) {
                        float e = fast_exp2(acc[t][jj] * KEXP);
                        if (lrow == kq * 4 + jj) e = 0.0f; // exclude self
                        rowsum[t][jj] += e;
                        csum += e;
                    }
                } else {
                    #pragma unroll
                    for (int jj = 0; jj < 4; ++jj) {
                        float e = fast_exp2(acc[t][jj] * KEXP);
                        rowsum[t][jj] += e;
                        csum += e;
                    }
                }
            }
            // col-sum: reduce across kq groups, accumulate into LDS
            csum += __shfl_xor(csum, 16);
            csum += __shfl_xor(csum, 32);
            if (kq == 0)
                colred[wv][tile * TILE_COLS + cs * 16 + lrow] += csum;
        }
        __syncthreads();   // next tile staged; reads of buf[cur] done
    }
#undef STAGE

    // rowsum: reduce across the 16 lrow lanes -> partial[2j+h][row]
    const int slotR = j * 2 + h;
    #pragma unroll
    for (int t = 0; t < 2; ++t)
        #pragma unroll
        for (int jj = 0; jj < 4; ++jj) {
            float v = rowsum[t][jj];
            v += __shfl_xor(v, 1);
            v += __shfl_xor(v, 2);
            v += __shfl_xor(v, 4);
            v += __shfl_xor(v, 8);
            if (lrow == 0)
                partial[(size_t)slotR * N_TOT + rowBase + t * 16 + kq * 4 + jj] = v;
        }

    // colsum: cross-wave reduce (visible after final __syncthreads)
    if (i != j && threadIdx.x < 128) {
        int c = threadIdx.x;
        float s = colred[0][c] + colred[1][c] + colred[2][c] + colred[3][c];
        partial[(size_t)(64 + 2 * i + g) * N_TOT + colStart + c] = s;
    }
}

// Kernel 3: one wave per row: S = sum of valid slots; lse = log(S);
// pos = 2*dot over permuted rows (permutation-invariant).
__global__ __launch_bounds__(256) void lse_kernel(const unsigned char* __restrict__ znP,
                                                  const float* __restrict__ partial,
                                                  float* __restrict__ blockSums) {
    const int lane = threadIdx.x & 63;
    const int wv   = threadIdx.x >> 6;
    const int r    = blockIdx.x * 4 + wv;
    const int rb   = r >> 8;
    const int rp   = r ^ HALF_B;
    uchar4 va = *reinterpret_cast<const uchar4*>(znP + (size_t)r  * DIM + lane * 4);
    uchar4 vb = *reinterpret_cast<const uchar4*>(znP + (size_t)rp * DIM + lane * 4);
    float d = fp82f(va.x) * fp82f(vb.x) + fp82f(va.y) * fp82f(vb.y) +
              fp82f(va.z) * fp82f(vb.z) + fp82f(va.w) * fp82f(vb.w);
    float S = 0.0f;
    if (lane >= 2 * rb) S += partial[(size_t)lane * N_TOT + r];          // rowsum slots
    if (lane < 2 * rb)  S += partial[(size_t)(64 + lane) * N_TOT + r];   // colsum slots
    #pragma unroll
    for (int off = 32; off; off >>= 1) {
        d += __shfl_xor(d, off);
        S += __shfl_xor(S, off);
    }
    __shared__ float red[4];
    if (lane == 0) red[wv] = logf(S) - d * 2.0f;
    __syncthreads();
    if (threadIdx.x == 0)
        blockSums[blockIdx.x] = red[0] + red[1] + red[2] + red[3];
}

// Kernel 4: reduce 2048 block sums -> loss
__global__ __launch_bounds__(256) void final_kernel(const float* __restrict__ bs,
                                                    float* __restrict__ out) {
    int t = threadIdx.x;
    float v = 0.0f;
    #pragma unroll
    for (int q = 0; q < LSE_BLOCKS / 256; ++q) v += bs[t + q * 256];
    #pragma unroll
    for (int off = 32; off; off >>= 1) v += __shfl_xor(v, off);
    __shared__ float red[4];
    if ((t & 63) == 0) red[t >> 6] = v;
    __syncthreads();
    if (t == 0) out[0] = (red[0] + red[1] + red[2] + red[3]) / (float)N_TOT;
}

extern "C" void kernel_launch(void* const* d_in, const int* in_sizes, int n_in,
                              void* d_out, int out_size, void* d_ws, size_t ws_size,
                              hipStream_t stream) {
    const float* zi = (const float*)d_in[0];
    const float* zj = (const float*)d_in[1];
    char* ws = (char*)d_ws;

    unsigned char* znP = (unsigned char*)ws;                         // 2 MB
    float* partial    = (float*)(znP + (size_t)N_TOT * DIM);         // 128 slots = 4 MB
    float* blockSums  = partial + (size_t)NSLOT * N_TOT;             // 8 KB
    float* out        = (float*)d_out;

    norm_kernel<<<N_TOT / 4, 256, 0, stream>>>(zi, zj, znP);
    sim_kernel<<<NBLK, 256, 0, stream>>>(znP, partial);
    lse_kernel<<<LSE_BLOCKS, 256, 0, stream>>>(znP, partial, blockSums);
    final_kernel<<<1, 256, 0, stream>>>(blockSums, out);
}